// Round 2
// baseline (475.804 us; speedup 1.0000x reference)
//
#include <hip/hip_runtime.h>

// HingeRankLoss on MI355X (gfx950).
// B=32768 rows, L=2048 cols. scores fp32, candidate_lengths int32, labels int32.
// Output: single fp32 scalar.
//
// Memory-bound: only the valid prefix (j < len) of each row matters for both
// pos and neg masks, so we read only that prefix (~268 MB avg vs 512 MB full).
// One 512-thread block per row: each thread owns exactly one float4 + int4
// (512*4 == 2048), predicated on j < len. Row data stays in registers across
// the two phases (pos-score block-reduce -> hinge sum), so there is exactly
// one global read of each byte.

constexpr int L_DIM = 2048;
constexpr float MARGIN = 0.1f;
constexpr int NBUCKET = 1024;  // spread-atomic accumulator buckets in d_ws

__global__ __launch_bounds__(512) void hinge_row_kernel(
    const float* __restrict__ scores,
    const int*   __restrict__ lens,
    const int*   __restrict__ labels,
    float* __restrict__ acc_sum,   // [NBUCKET]
    float* __restrict__ acc_cnt)   // [NBUCKET]
{
    const int row = blockIdx.x;
    int len = lens[row];
    if (len <= 0) return;              // uniform per block: no barrier hazard
    if (len > L_DIM) len = L_DIM;

    const int t = threadIdx.x;
    const size_t base = (size_t)row * L_DIM;
    const float4* s4 = reinterpret_cast<const float4*>(scores + base);
    const int4*   l4 = reinterpret_cast<const int4*>(labels + base);

    float se[4];                  // kept in registers between phases
    unsigned negmask = 0;
    float pos_local = 0.f;
    float haspos_local = 0.f;

    const int j = t * 4;          // element index of this thread's quad
    if (j < len) {
        const float4 sv = s4[t];
        const int4   lv = l4[t];
        se[0] = sv.x; se[1] = sv.y; se[2] = sv.z; se[3] = sv.w;
        const int le[4] = {lv.x, lv.y, lv.z, lv.w};
        #pragma unroll
        for (int e = 0; e < 4; ++e) {
            if (j + e < len) {
                if (le[e] == 1) { pos_local += se[e]; haspos_local = 1.f; }
                else            { negmask |= 1u << e; }
            }
        }
    }

    // ---- block reduce (pos_local, haspos_local): wave shfl + LDS across 8 waves
    float a = pos_local, b = haspos_local;
    #pragma unroll
    for (int off = 32; off > 0; off >>= 1) {
        a += __shfl_down(a, off, 64);
        b += __shfl_down(b, off, 64);
    }
    __shared__ float red_a[8], red_b[8];
    const int wave = t >> 6;
    const int lane = t & 63;
    if (lane == 0) { red_a[wave] = a; red_b[wave] = b; }
    __syncthreads();
    float pos_score = 0.f, has_pos = 0.f;
    #pragma unroll
    for (int i = 0; i < 8; ++i) { pos_score += red_a[i]; has_pos += red_b[i]; }

    const float chosen = (has_pos > 0.f) ? pos_score : -MARGIN;

    // ---- phase 2: hinge over this thread's negative valid elements (registers)
    float hsum = 0.f, hcnt = 0.f;
    #pragma unroll
    for (int e = 0; e < 4; ++e) {
        if (negmask & (1u << e)) {
            hsum += fmaxf(MARGIN + se[e] - chosen, 0.f);
            hcnt += 1.f;
        }
    }
    #pragma unroll
    for (int off = 32; off > 0; off >>= 1) {
        hsum += __shfl_down(hsum, off, 64);
        hcnt += __shfl_down(hcnt, off, 64);
    }
    __shared__ float red_h[8], red_c[8];
    if (lane == 0) { red_h[wave] = hsum; red_c[wave] = hcnt; }
    __syncthreads();
    if (t == 0) {
        float H = 0.f, C = 0.f;
        #pragma unroll
        for (int i = 0; i < 8; ++i) { H += red_h[i]; C += red_c[i]; }
        if (C > 0.f) {   // valid_obs: len>0 (already known) && has_neg
            atomicAdd(&acc_sum[row & (NBUCKET - 1)], H / C);
            atomicAdd(&acc_cnt[row & (NBUCKET - 1)], 1.f);
        }
    }
}

__global__ __launch_bounds__(1024) void finalize_kernel(
    const float* __restrict__ acc_sum,
    const float* __restrict__ acc_cnt,
    float* __restrict__ out)
{
    const int t = threadIdx.x;
    float s = acc_sum[t];
    float c = acc_cnt[t];
    #pragma unroll
    for (int off = 32; off > 0; off >>= 1) {
        s += __shfl_down(s, off, 64);
        c += __shfl_down(c, off, 64);
    }
    __shared__ float sh_s[16], sh_c[16];
    const int wave = t >> 6, lane = t & 63;
    if (lane == 0) { sh_s[wave] = s; sh_c[wave] = c; }
    __syncthreads();
    if (t == 0) {
        float S = 0.f, C = 0.f;
        #pragma unroll
        for (int i = 0; i < 16; ++i) { S += sh_s[i]; C += sh_c[i]; }
        out[0] = (C > 0.f) ? (S / C) : 0.f;
    }
}

extern "C" void kernel_launch(void* const* d_in, const int* in_sizes, int n_in,
                              void* d_out, int out_size, void* d_ws, size_t ws_size,
                              hipStream_t stream) {
    const float* scores = (const float*)d_in[0];
    const int*   lens   = (const int*)d_in[1];
    const int*   labels = (const int*)d_in[2];
    const int B = in_sizes[1];                 // candidate_lengths element count

    float* acc_sum = (float*)d_ws;
    float* acc_cnt = acc_sum + NBUCKET;

    // d_ws is re-poisoned 0xAA before every timed launch: zero our buckets.
    hipMemsetAsync(d_ws, 0, 2 * NBUCKET * sizeof(float), stream);

    hinge_row_kernel<<<B, 512, 0, stream>>>(scores, lens, labels, acc_sum, acc_cnt);
    finalize_kernel<<<1, NBUCKET, 0, stream>>>(acc_sum, acc_cnt, (float*)d_out);
}

// Round 3
// 462.861 us; speedup vs baseline: 1.0280x; 1.0280x over previous
//
#include <hip/hip_runtime.h>

// HingeRankLoss on MI355X (gfx950).
// B=32768 rows, L=2048 cols. scores fp32, candidate_lengths int32, labels int32.
// Output: single fp32 scalar.
//
// Memory-bound: only the valid prefix (j < len) of each row matters, so we
// read only that prefix (~268 MB avg vs 512 MB full).
//
// Wave-per-row layout: one 64-lane wave owns one row (4 rows per 256-thread
// block). All reductions are shfl_xor butterflies -> no __syncthreads, no LDS.
// Short rows exit the load loop at 256-element step granularity (uniform
// branch on readfirstlane(len)), so per-row time scales with len. Row data
// stays in registers across the two phases (pos-score reduce -> hinge sum):
// exactly one global read of each byte.

constexpr int L_DIM = 2048;
constexpr float MARGIN = 0.1f;
constexpr int NBUCKET = 1024;  // spread-atomic accumulator buckets in d_ws
constexpr int WPB = 4;         // waves (rows) per block

__global__ __launch_bounds__(256) void hinge_row_kernel(
    const float* __restrict__ scores,
    const int*   __restrict__ lens,
    const int*   __restrict__ labels,
    int B,
    float* __restrict__ acc_sum,   // [NBUCKET]
    float* __restrict__ acc_cnt)   // [NBUCKET]
{
    const int t    = threadIdx.x;
    const int wave = t >> 6;
    const int lane = t & 63;
    const int row  = blockIdx.x * WPB + wave;
    if (row >= B) return;

    int len = __builtin_amdgcn_readfirstlane(lens[row]);  // wave-uniform -> SGPR
    if (len <= 0) return;
    if (len > L_DIM) len = L_DIM;

    const size_t base = (size_t)row * L_DIM;
    const float4* s4 = reinterpret_cast<const float4*>(scores + base);
    const int4*   l4 = reinterpret_cast<const int4*>(labels + base);

    float se[32];                  // this lane's scores, registers, static idx
    unsigned negmask = 0;          // bit (k*4+e) = valid negative
    float pos_local = 0.f, haspos_local = 0.f;

    #pragma unroll
    for (int k = 0; k < 8; ++k) {
        if (k * 256 >= len) break;            // wave-uniform step skip
        const int v = k * 64 + lane;          // float4 index in row
        const int j = v * 4;                  // element index
        if (j < len) {                        // per-lane only at boundary step
            const float4 sv = s4[v];
            const int4   lv = l4[v];
            const float sve[4] = {sv.x, sv.y, sv.z, sv.w};
            const int    lve[4] = {lv.x, lv.y, lv.z, lv.w};
            #pragma unroll
            for (int e = 0; e < 4; ++e) {
                if (j + e < len) {
                    if (lve[e] == 1) { pos_local += sve[e]; haspos_local = 1.f; }
                    else             { se[k * 4 + e] = sve[e];
                                       negmask |= 1u << (k * 4 + e); }
                }
            }
        }
    }

    // ---- wave butterfly reduce (pos, haspos): every lane gets the sum
    #pragma unroll
    for (int off = 1; off < 64; off <<= 1) {
        pos_local    += __shfl_xor(pos_local, off, 64);
        haspos_local += __shfl_xor(haspos_local, off, 64);
    }
    const float chosen = (haspos_local > 0.f) ? pos_local : -MARGIN;

    // ---- phase 2: hinge over this lane's valid negatives (registers)
    float hsum = 0.f, hcnt = 0.f;
    #pragma unroll
    for (int i = 0; i < 32; ++i) {
        if (negmask & (1u << i)) {
            hsum += fmaxf(MARGIN + se[i] - chosen, 0.f);
            hcnt += 1.f;
        }
    }
    #pragma unroll
    for (int off = 1; off < 64; off <<= 1) {
        hsum += __shfl_xor(hsum, off, 64);
        hcnt += __shfl_xor(hcnt, off, 64);
    }
    if (lane == 0 && hcnt > 0.f) {  // valid_obs: len>0 && has_neg
        atomicAdd(&acc_sum[row & (NBUCKET - 1)], hsum / hcnt);
        atomicAdd(&acc_cnt[row & (NBUCKET - 1)], 1.f);
    }
}

__global__ __launch_bounds__(1024) void finalize_kernel(
    const float* __restrict__ acc_sum,
    const float* __restrict__ acc_cnt,
    float* __restrict__ out)
{
    const int t = threadIdx.x;
    float s = acc_sum[t];
    float c = acc_cnt[t];
    #pragma unroll
    for (int off = 32; off > 0; off >>= 1) {
        s += __shfl_down(s, off, 64);
        c += __shfl_down(c, off, 64);
    }
    __shared__ float sh_s[16], sh_c[16];
    const int wave = t >> 6, lane = t & 63;
    if (lane == 0) { sh_s[wave] = s; sh_c[wave] = c; }
    __syncthreads();
    if (t == 0) {
        float S = 0.f, C = 0.f;
        #pragma unroll
        for (int i = 0; i < 16; ++i) { S += sh_s[i]; C += sh_c[i]; }
        out[0] = (C > 0.f) ? (S / C) : 0.f;
    }
}

extern "C" void kernel_launch(void* const* d_in, const int* in_sizes, int n_in,
                              void* d_out, int out_size, void* d_ws, size_t ws_size,
                              hipStream_t stream) {
    const float* scores = (const float*)d_in[0];
    const int*   lens   = (const int*)d_in[1];
    const int*   labels = (const int*)d_in[2];
    const int B = in_sizes[1];                 // candidate_lengths element count

    float* acc_sum = (float*)d_ws;
    float* acc_cnt = acc_sum + NBUCKET;

    // d_ws is re-poisoned 0xAA before every timed launch: zero our buckets.
    hipMemsetAsync(d_ws, 0, 2 * NBUCKET * sizeof(float), stream);

    const int grid = (B + WPB - 1) / WPB;
    hinge_row_kernel<<<grid, 256, 0, stream>>>(scores, lens, labels, B,
                                               acc_sum, acc_cnt);
    finalize_kernel<<<1, NBUCKET, 0, stream>>>(acc_sum, acc_cnt, (float*)d_out);
}